// Round 3
// baseline (217.730 us; speedup 1.0000x reference)
//
#include <hip/hip_runtime.h>
#include <hip/hip_bf16.h>

typedef __attribute__((ext_vector_type(8))) __bf16 bf16x8;
typedef __attribute__((ext_vector_type(4))) float f32x4;
typedef __attribute__((ext_vector_type(4))) int int4v;

#define NB 8
#define NN 2048
#define ND 256
#define NTOT (NB * NN * ND)  // 4194304 floats = 16 MB

// ---------------------------------------------------------------------------
// K0: wl[d] = sum_o a[o]*W[o][d], wr[d] = sum_o a[256+o]*W[o][d]
// ---------------------------------------------------------------------------
__global__ __launch_bounds__(256) void k0_wvec(
    const float* __restrict__ W, const float* __restrict__ a,
    float* __restrict__ wl, float* __restrict__ wr) {
  int w = threadIdx.x >> 6, l = threadIdx.x & 63;
  f32x4 sl = {0.f, 0.f, 0.f, 0.f}, sr = {0.f, 0.f, 0.f, 0.f};
  for (int oo = 0; oo < 64; ++oo) {
    int o = w * 64 + oo;
    f32x4 wv = *(const f32x4*)(W + o * ND + l * 4);
    float al = a[o], ar = a[ND + o];
    sl += al * wv;
    sr += ar * wv;
  }
  __shared__ f32x4 bl[4][64], br[4][64];
  bl[w][l] = sl;
  br[w][l] = sr;
  __syncthreads();
  if (w == 0) {
    f32x4 tl = bl[0][l] + bl[1][l] + bl[2][l] + bl[3][l];
    f32x4 tr = br[0][l] + br[1][l] + br[2][l] + br[3][l];
    *(f32x4*)(wl + l * 4) = tl;
    *(f32x4*)(wr + l * 4) = tr;
  }
}

// ---------------------------------------------------------------------------
// K2: el[bn] = x[bn,:]*wl (f32), er[bn] = x[bn,:]*wr. 64 rows/block, 4 thr/row.
// ---------------------------------------------------------------------------
__global__ __launch_bounds__(256) void k2_elr(
    const float* __restrict__ x, const float* __restrict__ wl,
    const float* __restrict__ wr, float* __restrict__ el,
    float* __restrict__ er) {
  int t = threadIdx.x;
  int r = t >> 2, q = t & 3;
  long row = (long)blockIdx.x * 64 + r;
  const f32x4* xr = (const f32x4*)(x + row * ND);
  const f32x4* wl4 = (const f32x4*)wl;
  const f32x4* wr4 = (const f32x4*)wr;
  float sl = 0.f, sr = 0.f;
#pragma unroll
  for (int ii = 0; ii < 16; ++ii) {
    int idx = q + (ii << 2);
    f32x4 xv = xr[idx];
    f32x4 lv = wl4[idx];
    f32x4 rv = wr4[idx];
    sl += xv[0] * lv[0] + xv[1] * lv[1] + xv[2] * lv[2] + xv[3] * lv[3];
    sr += xv[0] * rv[0] + xv[1] * rv[1] + xv[2] * rv[2] + xv[3] * rv[3];
  }
  sl += __shfl_xor(sl, 1);
  sl += __shfl_xor(sl, 2);
  sr += __shfl_xor(sr, 1);
  sr += __shfl_xor(sr, 2);
  if (q == 0) {
    el[row] = sl;
    er[row] = sr;
  }
}

// ---------------------------------------------------------------------------
// K1: h = x @ W^T via bf16 MFMA 16x16x32; write hT[b][d][n] bf16 (transposed
// through LDS, stride padded to 34 to kill bank conflicts on the read-out).
// ---------------------------------------------------------------------------
__global__ __launch_bounds__(256) void k1_h(
    const float* __restrict__ x, const float* __restrict__ W,
    __bf16* __restrict__ hT) {
  __shared__ __bf16 hlds[256 * 34];
  int tid = threadIdx.x;
  int wid = tid >> 6, lane = tid & 63;
  int msub = wid & 1, nh = wid >> 1;
  int lrow = lane & 15, kg = lane >> 4;
  int m0 = blockIdx.x * 32;
  int row = m0 + msub * 16 + lrow;

  f32x4 acc[8];
#pragma unroll
  for (int f = 0; f < 8; ++f) acc[f] = (f32x4){0.f, 0.f, 0.f, 0.f};

#pragma unroll
  for (int k0 = 0; k0 < ND; k0 += 32) {
    int kk = k0 + kg * 8;
    const f32x4* xa = (const f32x4*)(x + (long)row * ND + kk);
    f32x4 a0 = xa[0], a1 = xa[1];
    bf16x8 afrag;
    afrag[0] = (__bf16)a0[0]; afrag[1] = (__bf16)a0[1];
    afrag[2] = (__bf16)a0[2]; afrag[3] = (__bf16)a0[3];
    afrag[4] = (__bf16)a1[0]; afrag[5] = (__bf16)a1[1];
    afrag[6] = (__bf16)a1[2]; afrag[7] = (__bf16)a1[3];
#pragma unroll
    for (int f = 0; f < 8; ++f) {
      int o = nh * 128 + f * 16 + lrow;
      const f32x4* wb = (const f32x4*)(W + (long)o * ND + kk);
      f32x4 b0 = wb[0], b1 = wb[1];
      bf16x8 bfrag;
      bfrag[0] = (__bf16)b0[0]; bfrag[1] = (__bf16)b0[1];
      bfrag[2] = (__bf16)b0[2]; bfrag[3] = (__bf16)b0[3];
      bfrag[4] = (__bf16)b1[0]; bfrag[5] = (__bf16)b1[1];
      bfrag[6] = (__bf16)b1[2]; bfrag[7] = (__bf16)b1[3];
      acc[f] = __builtin_amdgcn_mfma_f32_16x16x32_bf16(afrag, bfrag, acc[f], 0, 0, 0);
    }
  }

#pragma unroll
  for (int f = 0; f < 8; ++f) {
    int d = nh * 128 + f * 16 + lrow;
#pragma unroll
    for (int r = 0; r < 4; ++r) {
      int nloc = msub * 16 + kg * 4 + r;
      hlds[d * 34 + nloc] = (__bf16)acc[f][r];
    }
  }
  __syncthreads();
  {
    int b = m0 >> 11;
    int n0 = m0 & (NN - 1);
    const int* src = (const int*)(hlds + tid * 34);
    int tmp[16];
#pragma unroll
    for (int j = 0; j < 16; ++j) tmp[j] = src[j];
    __bf16* dst = hT + ((long)b * ND + tid) * NN + n0;
#pragma unroll
    for (int j = 0; j < 4; ++j)
      *(int4v*)(dst + j * 8) = *(int4v*)(tmp + j * 4);
  }
}

// ---------------------------------------------------------------------------
// K3: fused mask + softmax-numerator/denominator + PV over a j-CHUNK.
// p_ij = adj ? exp(lrelu(el_i+er_j) - (el_i+16)) : 0   (el_i+16 >= all scores)
// Grid = 512*split blocks, 256 thr (4 waves: isub=w&1, dh=w>>1).
// blk -> b = blk&7 (batch->XCD pin), it = (blk>>3)&63, jc = blk>>9.
// split==1: normalize + write out directly. split>1: write f32 partial num
// tile (out layout, region jc) + per-row partial den.
// ---------------------------------------------------------------------------
__global__ __launch_bounds__(256, 4) void k3_main(
    const int* __restrict__ adj, const __bf16* __restrict__ hT,
    const float* __restrict__ el, const float* __restrict__ er,
    float* __restrict__ num, float* __restrict__ denw,
    float* __restrict__ out, int split) {
  int blk = blockIdx.x;
  int b = blk & 7;
  int rest = blk >> 3;
  int it = rest & 63;
  int jc = rest >> 6;
  int nsteps = 64 / split;
  int t0 = jc * nsteps, tend = t0 + nsteps;

  int wid = threadIdx.x >> 6, lane = threadIdx.x & 63;
  int isub = wid & 1, dh = wid >> 1;
  int lrow = lane & 15, kg = lane >> 4;
  int irow = it * 32 + isub * 16 + lrow;

  float eli = el[b * NN + irow];
  float el16 = eli + 16.0f;
  const int* adjrow = adj + ((long)b * NN + irow) * NN;
  const float* erb = er + b * NN;
  int d_base = dh * 128 + lrow;
  int jb0 = kg * 8;
  const __bf16* hptr = hT + (long)b * ND * NN + (long)d_base * NN + jb0;

  f32x4 acc[8];
#pragma unroll
  for (int f = 0; f < 8; ++f) acc[f] = (f32x4){0.f, 0.f, 0.f, 0.f};
  float den = 0.f;

  // 1-deep prefetch of the adj/er stream (HBM/L3); hT comes from hot L2.
  int off0 = t0 * 32 + jb0;
  int4v adjA = *(const int4v*)(adjrow + off0);
  int4v adjB = *(const int4v*)(adjrow + off0 + 4);
  f32x4 erA = *(const f32x4*)(erb + off0);
  f32x4 erB = *(const f32x4*)(erb + off0 + 4);

  for (int t = t0; t < tend; ++t) {
    int4v cadjA = adjA, cadjB = adjB;
    f32x4 cerA = erA, cerB = erB;
    if (t + 1 < tend) {
      int off = (t + 1) * 32 + jb0;
      adjA = *(const int4v*)(adjrow + off);
      adjB = *(const int4v*)(adjrow + off + 4);
      erA = *(const f32x4*)(erb + off);
      erB = *(const f32x4*)(erb + off + 4);
    }
    // issue the 8 B-frag loads up-front so they overlap the exp VALU work
    bf16x8 bf[8];
#pragma unroll
    for (int f = 0; f < 8; ++f)
      bf[f] = *(const bf16x8*)(hptr + (long)f * 16 * NN + t * 32);

    bf16x8 pfrag;
    float ps = 0.f;
#pragma unroll
    for (int e = 0; e < 8; ++e) {
      int aj = (e < 4) ? cadjA[e] : cadjB[e - 4];
      float erx = (e < 4) ? cerA[e] : cerB[e - 4];
      float z = eli + erx;
      float s = fmaxf(z, 0.2f * z);  // leaky relu
      float p = __expf(s - el16);
      p = (aj != 0) ? p : 0.0f;
      ps += p;
      pfrag[e] = (__bf16)p;
    }
    den += ps;
#pragma unroll
    for (int f = 0; f < 8; ++f)
      acc[f] = __builtin_amdgcn_mfma_f32_16x16x32_bf16(pfrag, bf[f], acc[f], 0, 0, 0);
  }

  // den: sum across the 4 k-groups (lanes with same l&15)
  den += __shfl_xor(den, 16);
  den += __shfl_xor(den, 32);

  if (split == 1) {
    float rdiv[4];
#pragma unroll
    for (int r = 0; r < 4; ++r) rdiv[r] = 1.0f / __shfl(den, kg * 4 + r);
    float* outb = out + ((long)b * NN + it * 32 + isub * 16) * ND;
#pragma unroll
    for (int f = 0; f < 8; ++f) {
      int dcol = d_base + f * 16;
#pragma unroll
      for (int r = 0; r < 4; ++r)
        outb[(long)(kg * 4 + r) * ND + dcol] = acc[f][r] * rdiv[r];
    }
  } else {
    if (dh == 0 && kg == 0)  // lane l<16 holds den for row lrow
      denw[(long)jc * (NB * NN) + b * NN + irow] = den;
    float* numb = num + (long)jc * NTOT + ((long)b * NN + it * 32 + isub * 16) * ND;
#pragma unroll
    for (int f = 0; f < 8; ++f) {
      int dcol = d_base + f * 16;
#pragma unroll
      for (int r = 0; r < 4; ++r)
        numb[(long)(kg * 4 + r) * ND + dcol] = acc[f][r];
    }
  }
}

// ---------------------------------------------------------------------------
// K4: out = (sum_s num_s) / (sum_s den_s). 1024 floats per block.
// ---------------------------------------------------------------------------
__global__ __launch_bounds__(256) void k4_reduce(
    const float* __restrict__ num, const float* __restrict__ denw,
    float* __restrict__ out, int split) {
  long fidx = ((long)blockIdx.x * 256 + threadIdx.x) * 4;
  int row = (int)(fidx >> 8);
  f32x4 s = {0.f, 0.f, 0.f, 0.f};
  float d = 0.f;
  for (int sp = 0; sp < split; ++sp) {
    s += *(const f32x4*)(num + (long)sp * NTOT + fidx);
    d += denw[(long)sp * (NB * NN) + row];
  }
  float r = 1.0f / d;
  f32x4 o = s * r;
  *(f32x4*)(out + fidx) = o;
}

// ---------------------------------------------------------------------------
extern "C" void kernel_launch(void* const* d_in, const int* in_sizes, int n_in,
                              void* d_out, int out_size, void* d_ws,
                              size_t ws_size, hipStream_t stream) {
  const float* x = (const float*)d_in[0];
  const int* adj = (const int*)d_in[1];
  const float* W = (const float*)d_in[2];
  const float* a = (const float*)d_in[3];
  float* out = (float*)d_out;

  char* ws = (char*)d_ws;
  const size_t base = 8u * 1024u * 1024u;
  __bf16* hT = (__bf16*)ws;                       // 8 MB
  float* el = (float*)(ws + base);                // 64 KB
  float* er = (float*)(ws + base + 65536u);       // 64 KB
  float* wl = (float*)(ws + base + 131072u);      // 1 KB
  float* wr = (float*)(ws + base + 132096u);      // 1 KB
  float* denw = (float*)(ws + base + 133120u);    // up to 4*64 KB
  const size_t num_off = base + 133120u + 262144u;
  float* num = (float*)(ws + num_off);            // split * 16 MB

  int split = 1;
  if (ws_size >= num_off + 4ull * NTOT * 4ull) split = 4;
  else if (ws_size >= num_off + 2ull * NTOT * 4ull) split = 2;

  k0_wvec<<<dim3(1), dim3(256), 0, stream>>>(W, a, wl, wr);
  k2_elr<<<dim3(256), dim3(256), 0, stream>>>(x, wl, wr, el, er);
  k1_h<<<dim3(512), dim3(256), 0, stream>>>(x, W, hT);
  k3_main<<<dim3(512 * split), dim3(256), 0, stream>>>(adj, hT, el, er, num,
                                                       denw, out, split);
  if (split > 1)
    k4_reduce<<<dim3(NTOT / 1024), dim3(256), 0, stream>>>(num, denw, out,
                                                           split);
}

// Round 4
// 148.555 us; speedup vs baseline: 1.4657x; 1.4657x over previous
//
#include <hip/hip_runtime.h>
#include <hip/hip_bf16.h>

typedef __attribute__((ext_vector_type(8))) __bf16 bf16x8;
typedef __attribute__((ext_vector_type(4))) float f32x4;
typedef __attribute__((ext_vector_type(4))) int int4v;

#define NB 8
#define NN 2048
#define ND 256

// ---------------------------------------------------------------------------
// K0: wl[d] = sum_o a[o]*W[o][d], wr[d] = sum_o a[256+o]*W[o][d]
// ---------------------------------------------------------------------------
__global__ __launch_bounds__(256) void k0_wvec(
    const float* __restrict__ W, const float* __restrict__ a,
    float* __restrict__ wl, float* __restrict__ wr) {
  int w = threadIdx.x >> 6, l = threadIdx.x & 63;
  f32x4 sl = {0.f, 0.f, 0.f, 0.f}, sr = {0.f, 0.f, 0.f, 0.f};
  for (int oo = 0; oo < 64; ++oo) {
    int o = w * 64 + oo;
    f32x4 wv = *(const f32x4*)(W + o * ND + l * 4);
    float al = a[o], ar = a[ND + o];
    sl += al * wv;
    sr += ar * wv;
  }
  __shared__ f32x4 bl[4][64], br[4][64];
  bl[w][l] = sl;
  br[w][l] = sr;
  __syncthreads();
  if (w == 0) {
    f32x4 tl = bl[0][l] + bl[1][l] + bl[2][l] + bl[3][l];
    f32x4 tr = br[0][l] + br[1][l] + br[2][l] + br[3][l];
    *(f32x4*)(wl + l * 4) = tl;
    *(f32x4*)(wr + l * 4) = tr;
  }
}

// ---------------------------------------------------------------------------
// K2: el[bn] = x[bn,:]*wl (f32), er[bn] = x[bn,:]*wr.
// ---------------------------------------------------------------------------
__global__ __launch_bounds__(256) void k2_elr(
    const float* __restrict__ x, const float* __restrict__ wl,
    const float* __restrict__ wr, float* __restrict__ el,
    float* __restrict__ er) {
  int t = threadIdx.x;
  int r = t >> 2, q = t & 3;
  long row = (long)blockIdx.x * 64 + r;
  const f32x4* xr = (const f32x4*)(x + row * ND);
  const f32x4* wl4 = (const f32x4*)wl;
  const f32x4* wr4 = (const f32x4*)wr;
  float sl = 0.f, sr = 0.f;
#pragma unroll
  for (int ii = 0; ii < 16; ++ii) {
    int idx = q + (ii << 2);
    f32x4 xv = xr[idx];
    f32x4 lv = wl4[idx];
    f32x4 rv = wr4[idx];
    sl += xv[0] * lv[0] + xv[1] * lv[1] + xv[2] * lv[2] + xv[3] * lv[3];
    sr += xv[0] * rv[0] + xv[1] * rv[1] + xv[2] * rv[2] + xv[3] * rv[3];
  }
  sl += __shfl_xor(sl, 1);
  sl += __shfl_xor(sl, 2);
  sr += __shfl_xor(sr, 1);
  sr += __shfl_xor(sr, 2);
  if (q == 0) {
    el[row] = sl;
    er[row] = sr;
  }
}

// ---------------------------------------------------------------------------
// K1: h = x @ W^T via bf16 MFMA; write hT[b][d][n] bf16 (transposed via LDS).
// ---------------------------------------------------------------------------
__global__ __launch_bounds__(256) void k1_h(
    const float* __restrict__ x, const float* __restrict__ W,
    __bf16* __restrict__ hT) {
  __shared__ __bf16 hlds[256 * 34];
  int tid = threadIdx.x;
  int wid = tid >> 6, lane = tid & 63;
  int msub = wid & 1, nh = wid >> 1;
  int lrow = lane & 15, kg = lane >> 4;
  int m0 = blockIdx.x * 32;
  int row = m0 + msub * 16 + lrow;

  f32x4 acc[8];
#pragma unroll
  for (int f = 0; f < 8; ++f) acc[f] = (f32x4){0.f, 0.f, 0.f, 0.f};

#pragma unroll
  for (int k0 = 0; k0 < ND; k0 += 32) {
    int kk = k0 + kg * 8;
    const f32x4* xa = (const f32x4*)(x + (long)row * ND + kk);
    f32x4 a0 = xa[0], a1 = xa[1];
    bf16x8 afrag;
    afrag[0] = (__bf16)a0[0]; afrag[1] = (__bf16)a0[1];
    afrag[2] = (__bf16)a0[2]; afrag[3] = (__bf16)a0[3];
    afrag[4] = (__bf16)a1[0]; afrag[5] = (__bf16)a1[1];
    afrag[6] = (__bf16)a1[2]; afrag[7] = (__bf16)a1[3];
#pragma unroll
    for (int f = 0; f < 8; ++f) {
      int o = nh * 128 + f * 16 + lrow;
      const f32x4* wb = (const f32x4*)(W + (long)o * ND + kk);
      f32x4 b0 = wb[0], b1 = wb[1];
      bf16x8 bfrag;
      bfrag[0] = (__bf16)b0[0]; bfrag[1] = (__bf16)b0[1];
      bfrag[2] = (__bf16)b0[2]; bfrag[3] = (__bf16)b0[3];
      bfrag[4] = (__bf16)b1[0]; bfrag[5] = (__bf16)b1[1];
      bfrag[6] = (__bf16)b1[2]; bfrag[7] = (__bf16)b1[3];
      acc[f] = __builtin_amdgcn_mfma_f32_16x16x32_bf16(afrag, bfrag, acc[f], 0, 0, 0);
    }
  }

#pragma unroll
  for (int f = 0; f < 8; ++f) {
    int d = nh * 128 + f * 16 + lrow;
#pragma unroll
    for (int r = 0; r < 4; ++r) {
      int nloc = msub * 16 + kg * 4 + r;
      hlds[d * 34 + nloc] = (__bf16)acc[f][r];
    }
  }
  __syncthreads();
  {
    int b = m0 >> 11;
    int n0 = m0 & (NN - 1);
    const int* src = (const int*)(hlds + tid * 34);
    int tmp[16];
#pragma unroll
    for (int j = 0; j < 16; ++j) tmp[j] = src[j];
    __bf16* dst = hT + ((long)b * ND + tid) * NN + n0;
#pragma unroll
    for (int j = 0; j < 4; ++j)
      *(int4v*)(dst + j * 8) = *(int4v*)(tmp + j * 4);
  }
}

// ---------------------------------------------------------------------------
// K5: pack adj (134 MB int32) into bitmask (4.2 MB). Pure HBM stream.
// Wave reads 64 consecutive ints, __ballot -> one uint64 (bit l = j0+l).
// ---------------------------------------------------------------------------
__global__ __launch_bounds__(256) void k5_pack(
    const int* __restrict__ adj, unsigned long long* __restrict__ mask) {
  const long NSEG = (long)NB * NN * (NN / 64);  // 524288
  int lane = threadIdx.x & 63;
  long gw = (((long)blockIdx.x * 256 + threadIdx.x) >> 6);
  long stride = ((long)gridDim.x * 256) >> 6;
  for (long s = gw; s < NSEG; s += stride) {
    int v = adj[s * 64 + lane];
    unsigned long long m = __ballot(v != 0);
    if (lane == 0) mask[s] = m;
  }
}

// ---------------------------------------------------------------------------
// K3: fused mask+softmax+PV, 2-phase LDS pipeline.
//  - hT j-chunks (64 j x 256 d = 32 KB) double-buffered via global_load_lds
//    width=16; source-side XOR swizzle so ds_read_b128 is bank-balanced.
//  - er (8 KB) + mask tile (32 rows x 64 words, padded stride 65) staged once.
//  - main loop: zero latency-critical global loads.
// p_ij = bit ? exp(lrelu(el_i+er_j) - (el_i+16)) : 0 ; el_i+16 >= all scores
// ---------------------------------------------------------------------------
__global__ __launch_bounds__(256, 2) void k3_main(
    const unsigned* __restrict__ mask, const __bf16* __restrict__ hT,
    const float* __restrict__ el, const float* __restrict__ er,
    float* __restrict__ out) {
  __shared__ __bf16 hbuf[2][256 * 64];    // 2 x 32 KB
  __shared__ float er_lds[NN];            // 8 KB
  __shared__ unsigned mask_lds[32 * 65];  // 8.1 KB, stride 65 = conflict-free

  int blk = blockIdx.x;
  int b = blk & 7;    // batch -> XCD pin
  int it = blk >> 3;  // i-tile 0..63
  int tid = threadIdx.x;
  int wid = tid >> 6, lane = tid & 63;
  int isub = wid & 1, dh = wid >> 1;
  int lrow = lane & 15, kg = lane >> 4;
  int irow = it * 32 + isub * 16 + lrow;

  const __bf16* hTb = hT + (long)b * ND * NN;
  const float* erb = er + (long)b * NN;
  const unsigned* maskb = mask + ((long)b * NN + (long)it * 32) * 64;

  // one-time stage: er + mask tile
  {
    f32x4 e0 = *(const f32x4*)(erb + tid * 8);
    f32x4 e1 = *(const f32x4*)(erb + tid * 8 + 4);
    *(f32x4*)(er_lds + tid * 8) = e0;
    *(f32x4*)(er_lds + tid * 8 + 4) = e1;
    int4v m0 = *(const int4v*)(maskb + tid * 8);
    int4v m1 = *(const int4v*)(maskb + tid * 8 + 4);
#pragma unroll
    for (int e = 0; e < 8; ++e) {
      int w = tid * 8 + e;
      unsigned val = (unsigned)((e < 4) ? m0[e] : m1[e - 4]);
      mask_lds[(w >> 6) * 65 + (w & 63)] = val;
    }
  }

  float eli = el[b * NN + irow];
  float el16 = eli + 16.0f;

  // stage one 64-j chunk of hT into dst; LDS dest linear (lane x 16B),
  // global source pre-swizzled: js = ((idx&7) ^ (d&7)) * 8
  auto stage = [&](__bf16* dst, int tc) {
    const __bf16* src = hTb + tc * 64;
#pragma unroll
    for (int r = 0; r < 8; ++r) {
      int idx = r * 256 + tid;
      int d = idx >> 3;
      int js = ((idx & 7) ^ (d & 7)) * 8;
      __builtin_amdgcn_global_load_lds(
          (const __attribute__((address_space(1))) void*)(src + (long)d * NN + js),
          (__attribute__((address_space(3))) void*)(dst + (long)idx * 8),
          16, 0, 0);
    }
  };

  f32x4 acc[8];
#pragma unroll
  for (int f = 0; f < 8; ++f) acc[f] = (f32x4){0.f, 0.f, 0.f, 0.f};
  float den = 0.f;
  int mrow = (isub * 16 + lrow) * 65;
  unsigned kgsh = kg * 8u;
  int swz = (lrow & 7) << 4;
  int d_base = dh * 128 + lrow;

  stage(hbuf[0], 0);
  __syncthreads();

  for (int tc = 0; tc < 32; ++tc) {
    const __bf16* cb = hbuf[tc & 1];
    if (tc < 31) stage(hbuf[(tc & 1) ^ 1], tc + 1);
#pragma unroll
    for (int t2 = 0; t2 < 2; ++t2) {
      int t = tc * 2 + t2;
      unsigned msh = mask_lds[mrow + t] >> kgsh;
      f32x4 ea = *(const f32x4*)(er_lds + t * 32 + kg * 8);
      f32x4 eb2 = *(const f32x4*)(er_lds + t * 32 + kg * 8 + 4);
      bf16x8 pfrag;
      float ps = 0.f;
#pragma unroll
      for (int e = 0; e < 8; ++e) {
        float erx = (e < 4) ? ea[e] : eb2[e - 4];
        float z = eli + erx;
        float s = fmaxf(z, 0.2f * z);  // leaky relu
        float p = __expf(s - el16);
        p = ((msh >> e) & 1u) ? p : 0.0f;
        ps += p;
        pfrag[e] = (__bf16)p;
      }
      den += ps;
#pragma unroll
      for (int f = 0; f < 8; ++f) {
        int d = d_base + f * 16;
        int byte = (d * 128 + t2 * 64 + kg * 16) ^ swz;
        bf16x8 bfr = *(const bf16x8*)((const char*)cb + byte);
        acc[f] = __builtin_amdgcn_mfma_f32_16x16x32_bf16(pfrag, bfr, acc[f], 0, 0, 0);
      }
    }
    __syncthreads();
  }

  // den: sum across the 4 k-groups (lanes with same l&15)
  den += __shfl_xor(den, 16);
  den += __shfl_xor(den, 32);
  float rdiv[4];
#pragma unroll
  for (int r = 0; r < 4; ++r) rdiv[r] = 1.0f / __shfl(den, kg * 4 + r);

  float* outb = out + ((long)b * NN + it * 32 + isub * 16) * ND;
#pragma unroll
  for (int f = 0; f < 8; ++f) {
    int dcol = d_base + f * 16;
#pragma unroll
    for (int r = 0; r < 4; ++r)
      outb[(long)(kg * 4 + r) * ND + dcol] = acc[f][r] * rdiv[r];
  }
}

// ---------------------------------------------------------------------------
extern "C" void kernel_launch(void* const* d_in, const int* in_sizes, int n_in,
                              void* d_out, int out_size, void* d_ws,
                              size_t ws_size, hipStream_t stream) {
  const float* x = (const float*)d_in[0];
  const int* adj = (const int*)d_in[1];
  const float* W = (const float*)d_in[2];
  const float* a = (const float*)d_in[3];
  float* out = (float*)d_out;

  char* ws = (char*)d_ws;
  const size_t base = 8u * 1024u * 1024u;
  __bf16* hT = (__bf16*)ws;                            // 8 MB
  float* el = (float*)(ws + base);                     // 64 KB
  float* er = (float*)(ws + base + 65536u);            // 64 KB
  float* wl = (float*)(ws + base + 131072u);           // 1 KB
  float* wr = (float*)(ws + base + 132096u);           // 1 KB
  unsigned long long* mask =
      (unsigned long long*)(ws + base + 262144u);      // 4 MB

  k5_pack<<<dim3(2048), dim3(256), 0, stream>>>(adj, mask);
  k0_wvec<<<dim3(1), dim3(256), 0, stream>>>(W, a, wl, wr);
  k2_elr<<<dim3(256), dim3(256), 0, stream>>>(x, wl, wr, el, er);
  k1_h<<<dim3(512), dim3(256), 0, stream>>>(x, W, hT);
  k3_main<<<dim3(512), dim3(256), 0, stream>>>((const unsigned*)mask, hT, el,
                                               er, out);
}

// Round 5
// 106.987 us; speedup vs baseline: 2.0351x; 1.3885x over previous
//
#include <hip/hip_runtime.h>
#include <hip/hip_bf16.h>

typedef __attribute__((ext_vector_type(8))) __bf16 bf16x8;
typedef __attribute__((ext_vector_type(4))) float f32x4;
typedef __attribute__((ext_vector_type(4))) int int4v;

#define NB 8
#define NN 2048
#define ND 256

// ---------------------------------------------------------------------------
// K2: fused (k0+k2): per block recompute wl/wr = W^T a halves (L2-hot W),
// then el/er row dots in f32. 256 blocks x 64 rows.
// ---------------------------------------------------------------------------
__global__ __launch_bounds__(256) void k2_elr(
    const float* __restrict__ x, const float* __restrict__ W,
    const float* __restrict__ a, float* __restrict__ el,
    float* __restrict__ er) {
  __shared__ float wls[ND], wrs[ND];
  int t = threadIdx.x;
  {
    float swl = 0.f, swr = 0.f;
    for (int o = 0; o < ND; ++o) {
      float wv = W[(long)o * ND + t];
      swl = fmaf(a[o], wv, swl);
      swr = fmaf(a[ND + o], wv, swr);
    }
    wls[t] = swl;
    wrs[t] = swr;
  }
  __syncthreads();
  int r = t >> 2, q = t & 3;
  long row = (long)blockIdx.x * 64 + r;
  const f32x4* xr = (const f32x4*)(x + row * ND);
  float sl = 0.f, sr = 0.f;
#pragma unroll
  for (int ii = 0; ii < 16; ++ii) {
    int idx = q + (ii << 2);
    f32x4 xv = xr[idx];
    f32x4 lv = *(const f32x4*)(wls + idx * 4);
    f32x4 rv = *(const f32x4*)(wrs + idx * 4);
    sl += xv[0] * lv[0] + xv[1] * lv[1] + xv[2] * lv[2] + xv[3] * lv[3];
    sr += xv[0] * rv[0] + xv[1] * rv[1] + xv[2] * rv[2] + xv[3] * rv[3];
  }
  sl += __shfl_xor(sl, 1);
  sl += __shfl_xor(sl, 2);
  sr += __shfl_xor(sr, 1);
  sr += __shfl_xor(sr, 2);
  if (q == 0) {
    el[row] = sl;
    er[row] = sr;
  }
}

// ---------------------------------------------------------------------------
// K1: h = x @ W^T via bf16 MFMA; write hT[b][d][n] bf16 (transposed via LDS).
// ---------------------------------------------------------------------------
__global__ __launch_bounds__(256) void k1_h(
    const float* __restrict__ x, const float* __restrict__ W,
    __bf16* __restrict__ hT) {
  __shared__ __bf16 hlds[256 * 34];
  int tid = threadIdx.x;
  int wid = tid >> 6, lane = tid & 63;
  int msub = wid & 1, nh = wid >> 1;
  int lrow = lane & 15, kg = lane >> 4;
  int m0 = blockIdx.x * 32;
  int row = m0 + msub * 16 + lrow;

  f32x4 acc[8];
#pragma unroll
  for (int f = 0; f < 8; ++f) acc[f] = (f32x4){0.f, 0.f, 0.f, 0.f};

#pragma unroll
  for (int k0 = 0; k0 < ND; k0 += 32) {
    int kk = k0 + kg * 8;
    const f32x4* xa = (const f32x4*)(x + (long)row * ND + kk);
    f32x4 a0 = xa[0], a1 = xa[1];
    bf16x8 afrag;
    afrag[0] = (__bf16)a0[0]; afrag[1] = (__bf16)a0[1];
    afrag[2] = (__bf16)a0[2]; afrag[3] = (__bf16)a0[3];
    afrag[4] = (__bf16)a1[0]; afrag[5] = (__bf16)a1[1];
    afrag[6] = (__bf16)a1[2]; afrag[7] = (__bf16)a1[3];
#pragma unroll
    for (int f = 0; f < 8; ++f) {
      int o = nh * 128 + f * 16 + lrow;
      const f32x4* wb = (const f32x4*)(W + (long)o * ND + kk);
      f32x4 b0 = wb[0], b1 = wb[1];
      bf16x8 bfrag;
      bfrag[0] = (__bf16)b0[0]; bfrag[1] = (__bf16)b0[1];
      bfrag[2] = (__bf16)b0[2]; bfrag[3] = (__bf16)b0[3];
      bfrag[4] = (__bf16)b1[0]; bfrag[5] = (__bf16)b1[1];
      bfrag[6] = (__bf16)b1[2]; bfrag[7] = (__bf16)b1[3];
      acc[f] = __builtin_amdgcn_mfma_f32_16x16x32_bf16(afrag, bfrag, acc[f], 0, 0, 0);
    }
  }

#pragma unroll
  for (int f = 0; f < 8; ++f) {
    int d = nh * 128 + f * 16 + lrow;
#pragma unroll
    for (int r = 0; r < 4; ++r) {
      int nloc = msub * 16 + kg * 4 + r;
      hlds[d * 34 + nloc] = (__bf16)acc[f][r];
    }
  }
  __syncthreads();
  {
    int b = m0 >> 11;
    int n0 = m0 & (NN - 1);
    const int* src = (const int*)(hlds + tid * 34);
    int tmp[16];
#pragma unroll
    for (int j = 0; j < 16; ++j) tmp[j] = src[j];
    __bf16* dst = hT + ((long)b * ND + tid) * NN + n0;
#pragma unroll
    for (int j = 0; j < 4; ++j)
      *(int4v*)(dst + j * 8) = *(int4v*)(tmp + j * 4);
  }
}

// ---------------------------------------------------------------------------
// K3: fused adj-stream + mask + softmax + PV.
// Chunk = 32 j. Triple-buffered LDS staging via global_load_lds (hT 16 KB +
// adj 4 KB per chunk), counted vmcnt(5) waits (loads span barriers; never
// drain-to-0 in the loop), raw s_barrier. 68 KB LDS -> 2 blocks/CU.
// p_ij = adj ? exp(lrelu(el_i+er_j) - (el_i+16)) : 0 ; el_i+16 >= all scores.
// Source-side XOR swizzles (linear LDS dest, swizzled global src + swizzled
// ds_read) keep b128 reads <=2-way per 16-lane phase.
// ---------------------------------------------------------------------------
__global__ __launch_bounds__(256, 2) void k3_main(
    const int* __restrict__ adj, const __bf16* __restrict__ hT,
    const float* __restrict__ el, const float* __restrict__ er,
    float* __restrict__ out) {
  __shared__ __bf16 hbuf[3][256 * 32];  // 3 x 16 KB
  __shared__ int abuf[3][32 * 32];      // 3 x 4 KB
  __shared__ float er_lds[NN];          // 8 KB

  int blk = blockIdx.x;
  int b = blk & 7;    // batch -> XCD pin (worked: FETCH showed L2-resident hT)
  int it = blk >> 3;  // i-tile 0..63
  int tid = threadIdx.x;
  int wid = tid >> 6, lane = tid & 63;
  int isub = wid & 1, dh = wid >> 1;
  int lrow = lane & 15, kg = lane >> 4;
  int irow = it * 32 + isub * 16 + lrow;

  const __bf16* hTb = hT + (long)b * ND * NN;
  const float* erb = er + (long)b * NN;
  const int* adjb = adj + ((long)b * NN + (long)it * 32) * NN;

  // one-time er staging
  {
    f32x4 e0 = *(const f32x4*)(erb + tid * 8);
    f32x4 e1 = *(const f32x4*)(erb + tid * 8 + 4);
    *(f32x4*)(er_lds + tid * 8) = e0;
    *(f32x4*)(er_lds + tid * 8 + 4) = e1;
  }
  float eli = el[b * NN + irow];
  float el16 = eli + 16.0f;

  // stage chunk tc (32 j) into buffer s: 4 hT loads + 1 adj load per thread.
  auto stage = [&](int s, int tc) {
    const __bf16* hsrc = hTb + tc * 32;
    __bf16* hdst = &hbuf[s][0];
#pragma unroll
    for (int r = 0; r < 4; ++r) {
      int idx = r * 256 + tid;  // 0..1023 : (d = idx>>2, slot = idx&3)
      int d = idx >> 2;
      int g = (idx & 3) ^ ((d & 3) ^ ((d >> 2) & 3));  // logical 8-j piece
      __builtin_amdgcn_global_load_lds(
          (const __attribute__((address_space(1))) void*)(hsrc + (long)d * NN + g * 8),
          (__attribute__((address_space(3))) void*)(hdst + idx * 8), 16, 0, 0);
    }
    int r2 = tid >> 3;               // adj row 0..31
    int g2 = (tid & 7) ^ (r2 & 7);   // logical 4-int piece
    __builtin_amdgcn_global_load_lds(
        (const __attribute__((address_space(1))) void*)(adjb + (long)r2 * NN + tc * 32 + g2 * 4),
        (__attribute__((address_space(3))) void*)(&abuf[s][0] + tid * 4), 16, 0, 0);
  };

  f32x4 acc[8];
#pragma unroll
  for (int f = 0; f < 8; ++f) acc[f] = (f32x4){0.f, 0.f, 0.f, 0.f};
  float den = 0.f;

  int d_base = dh * 128 + lrow;
  int hsw = (lrow & 3) ^ ((lrow >> 2) & 3);
  int hoff = d_base * 64 + ((kg ^ hsw) << 4);  // byte offset, +f*1024 per frag
  int rloc = isub * 16 + lrow;
  int swa = rloc & 7;
  int aoff0 = rloc * 128 + (((kg * 2) ^ swa) << 4);
  int aoff1 = rloc * 128 + (((kg * 2 + 1) ^ swa) << 4);

  stage(0, 0);
  stage(1, 1);
  __syncthreads();  // one-time full drain (chunks 0,1 resident after this)

  for (int tc = 0; tc < 64; ++tc) {
    if (tc < 63)
      asm volatile("s_waitcnt vmcnt(5)" ::: "memory");
    else
      asm volatile("s_waitcnt vmcnt(0)" ::: "memory");
    __builtin_amdgcn_s_barrier();
    asm volatile("" ::: "memory");
    if (tc + 2 < 64) stage((tc + 2) % 3, tc + 2);

    int cb = tc % 3;
    const char* ab = (const char*)(&abuf[cb][0]);
    int4v a0 = *(const int4v*)(ab + aoff0);
    int4v a1 = *(const int4v*)(ab + aoff1);
    f32x4 ea = *(const f32x4*)(er_lds + tc * 32 + kg * 8);
    f32x4 eb = *(const f32x4*)(er_lds + tc * 32 + kg * 8 + 4);

    bf16x8 pfrag;
    float ps = 0.f;
#pragma unroll
    for (int e = 0; e < 8; ++e) {
      int aj = (e < 4) ? a0[e] : a1[e - 4];
      float erx = (e < 4) ? ea[e] : eb[e - 4];
      float z = eli + erx;
      float s = fmaxf(z, 0.2f * z);  // leaky relu
      float p = __expf(s - el16);
      p = (aj != 0) ? p : 0.0f;
      ps += p;
      pfrag[e] = (__bf16)p;
    }
    den += ps;

    const char* hb = (const char*)(&hbuf[cb][0]);
#pragma unroll
    for (int f = 0; f < 8; ++f) {
      bf16x8 bfr = *(const bf16x8*)(hb + hoff + f * 1024);
      acc[f] = __builtin_amdgcn_mfma_f32_16x16x32_bf16(pfrag, bfr, acc[f], 0, 0, 0);
    }
  }

  // den: sum across the 4 k-groups (lanes with same l&15)
  den += __shfl_xor(den, 16);
  den += __shfl_xor(den, 32);
  float rdiv[4];
#pragma unroll
  for (int r = 0; r < 4; ++r) rdiv[r] = 1.0f / __shfl(den, kg * 4 + r);

  float* outb = out + ((long)b * NN + it * 32 + isub * 16) * ND;
#pragma unroll
  for (int f = 0; f < 8; ++f) {
    int dcol = d_base + f * 16;
#pragma unroll
    for (int r = 0; r < 4; ++r)
      outb[(long)(kg * 4 + r) * ND + dcol] = acc[f][r] * rdiv[r];
  }
}

// ---------------------------------------------------------------------------
extern "C" void kernel_launch(void* const* d_in, const int* in_sizes, int n_in,
                              void* d_out, int out_size, void* d_ws,
                              size_t ws_size, hipStream_t stream) {
  const float* x = (const float*)d_in[0];
  const int* adj = (const int*)d_in[1];
  const float* W = (const float*)d_in[2];
  const float* a = (const float*)d_in[3];
  float* out = (float*)d_out;

  char* ws = (char*)d_ws;
  const size_t base = 8u * 1024u * 1024u;
  __bf16* hT = (__bf16*)ws;                  // 8 MB
  float* el = (float*)(ws + base);           // 64 KB
  float* er = (float*)(ws + base + 65536u);  // 64 KB

  k1_h<<<dim3(512), dim3(256), 0, stream>>>(x, W, hT);
  k2_elr<<<dim3(256), dim3(256), 0, stream>>>(x, W, a, el, er);
  k3_main<<<dim3(512), dim3(256), 0, stream>>>(adj, hT, el, er, out);
}